// Round 11
// baseline (89.128 us; speedup 1.0000x reference)
//
#include <hip/hip_runtime.h>
#include <hip/hip_bf16.h>

// AttentionBlock: N=4, C=128, H=W=64 (L=4096), 32 groups.
// Fixed-softmax-max scheme: scores S*log2e ~ N(0,~1.4^2); max << FIXM=16.
// P = exp2(S-16); partials additive across splits.
// ws: [0,4KB) stats; q_ws [N][L][C] bf16; k_ws [N][L][C] bf16;
// v_ws [N][C][L] bf16 (m bit2<->bit3 permuted per 16-group);
// po_ws [N][32][SPLIT][128][128] bf16; md_ws f32; wbf [4][128][128] bf16;
// flags[64] u32 (per-key split counters, zeroed by gnw each launch).
//
// LESSONS: (R3/R4) launch_bounds min-waves=4 -> 64-VGPR cap -> spill disaster.
// (R0-R9) flash schedule experiments: 1-bar/step 45.5, counted vmcnt 45.7,
// intra-wave fold 43.9 (BEST), 8-phase 47.4, wave-split 48.7. Per step:
// MFMA 2066/SIMD + VALU ~1800/SIMD + LDS 3084/CU run SERIAL across ALL
// schedules -> structural plateau (~764 TF, matches m214 plain-HIP ceiling).
// (R10) qkv-merge/combine-split bought ~1us: non-flash 28.8us is ~19us
// memory floor + ~10us inter-kernel dead time.
// R11: fuse combine into flash tail. 4 split blocks of a key are co-resident
// (grid 256 = 1/CU); after po/md write: release-fence + flags[key]++, spin
// until 4, then each block combines its own 64-l quarter (quarter = split).

#define N_B 4
#define C_D 128
#define L_D 4096
#define SPLIT 4
#define KVB 64
#define FSTEPS ((L_D/SPLIT)/KVB)   // 16
#define QSCALE (0.08838834764831845f * 1.4426950408889634f)
#define FIXM 16.0f

using f32x4  = __attribute__((ext_vector_type(4))) float;
using f32x16 = __attribute__((ext_vector_type(16))) float;
using bf16x8 = __attribute__((ext_vector_type(8))) short;

static __device__ __forceinline__ unsigned short f2bf(float f){
  return (unsigned short)((__builtin_bit_cast(unsigned int, f) + 0x8000u) >> 16);
}
static __device__ __forceinline__ float bf2f(unsigned short u){
  unsigned int x = ((unsigned int)u) << 16;
  return __builtin_bit_cast(float, x);
}
static __device__ __forceinline__ unsigned int pk2(float a, float b){
  unsigned int ua = __builtin_bit_cast(unsigned int, a) + 0x8000u;
  unsigned int ub = __builtin_bit_cast(unsigned int, b) + 0x8000u;
  return __builtin_amdgcn_perm(ub, ua, 0x07060302u);
}
static __device__ __forceinline__ float exp2a(float x){
  float r; asm("v_exp_f32 %0, %1" : "=v"(r) : "v"(x)); return r;
}
static __device__ __forceinline__ void gll16(const void* g, void* l){
  __builtin_amdgcn_global_load_lds(
      (const __attribute__((address_space(1))) unsigned int*)g,
      (__attribute__((address_space(3))) unsigned int*)l, 16, 0, 0);
}

// ---------------- kernel 1: GroupNorm stats + weight->bf16 + flag clear ----
__global__ __launch_bounds__(256) void gnw_k(
    const float* __restrict__ x, float* __restrict__ stats,
    const float* __restrict__ wq, const float* __restrict__ wk,
    const float* __restrict__ wv, const float* __restrict__ wo,
    unsigned short* __restrict__ wbf, unsigned int* __restrict__ flags)
{
  int b = blockIdx.x, t = threadIdx.x;
  if (b >= 128){
    int b2 = b - 128;
    if (b2 == 0 && t < 64)
      __hip_atomic_store(&flags[t], 0u, __ATOMIC_RELAXED, __HIP_MEMORY_SCOPE_AGENT);
    int mat = b2 >> 4;
    const float* src = (mat == 0) ? wq : (mat == 1) ? wk : (mat == 2) ? wv : wo;
    int off = (b2 & 15) * 1024 + t * 4;
    float4 v = *(const float4*)(src + off);
    *(uint2*)(wbf + mat*16384 + off) = make_uint2(pk2(v.x, v.y), pk2(v.z, v.w));
    return;
  }
  const float4* p = (const float4*)(x + (size_t)b * (4 * L_D));
  float s = 0.f, ss = 0.f;
#pragma unroll
  for (int i = 0; i < 16; ++i){
    float4 v = p[t + i*256];
    s  += v.x + v.y + v.z + v.w;
    ss += v.x*v.x + v.y*v.y + v.z*v.z + v.w*v.w;
  }
#pragma unroll
  for (int off = 32; off > 0; off >>= 1){
    s  += __shfl_down(s, off);
    ss += __shfl_down(ss, off);
  }
  __shared__ float rs4[4], rss4[4];
  if ((t & 63) == 0){ rs4[t>>6] = s; rss4[t>>6] = ss; }
  __syncthreads();
  if (t == 0){
    s  = rs4[0]+rs4[1]+rs4[2]+rs4[3];
    ss = rss4[0]+rss4[1]+rss4[2]+rss4[3];
    float mean = s * (1.f/16384.f);
    float var  = ss * (1.f/16384.f) - mean*mean;
    if (var < 0.f) var = 0.f;
    stats[2*b]   = mean;
    stats[2*b+1] = rsqrtf(var + 1e-6f);
  }
}

// ---------------- kernel 2: GN-normalize + ALL THREE projections per block --
__global__ __launch_bounds__(256) void qkv_k(
    const float* __restrict__ x, const float* __restrict__ stats,
    const float* __restrict__ gamma, const float* __restrict__ beta,
    const unsigned short* __restrict__ wbf,
    const float* __restrict__ bq, const float* __restrict__ bk,
    const float* __restrict__ bv,
    unsigned short* __restrict__ q_ws, unsigned short* __restrict__ k_ws,
    unsigned short* __restrict__ v_ws)
{
  __shared__ unsigned short xnT[64][136];
  __shared__ unsigned short qbuf[64][136];

  int t = threadIdx.x, b = blockIdx.x;
  int n = b >> 6, l0 = (b & 63) * 64;

  { // stage xnT = groupnorm(x)^T once for this l-tile
    int l = t & 63, cq = t >> 6;
#pragma unroll
    for (int it = 0; it < 8; ++it){
      int c0 = cq*4 + it*16;
      int g  = c0 >> 2;
      float mean = stats[(n*32+g)*2];
      float rstd = stats[(n*32+g)*2+1];
      float vv[4];
#pragma unroll
      for (int jj = 0; jj < 4; ++jj){
        int c = c0 + jj;
        float sc = rstd * gamma[c];
        float bs = beta[c] - mean * sc;
        vv[jj] = x[(size_t)(n*C_D + c)*L_D + l0 + l]*sc + bs;
      }
      *(unsigned int*)&xnT[l][c0]   = pk2(vv[0], vv[1]);
      *(unsigned int*)&xnT[l][c0+2] = pk2(vv[2], vv[3]);
    }
  }
  __syncthreads();

  int w = t >> 6, lane = t & 63, u = lane >> 4, l15 = lane & 15;
  int wc = w >> 1, wl = w & 1;
  f32x4 zz = {0.f,0.f,0.f,0.f};

  for (int wi = 0; wi < 3; ++wi){
    const unsigned short* W = wbf + wi*16384;
    const float* Bv = (wi == 0) ? bq : (wi == 1) ? bk : bv;

    f32x4 acc[4][2];
#pragma unroll
    for (int ct = 0; ct < 4; ++ct)
#pragma unroll
      for (int lt = 0; lt < 2; ++lt) acc[ct][lt] = zz;

#pragma unroll
    for (int kst = 0; kst < 4; ++kst){
      bf16x8 bfrag[2];
#pragma unroll
      for (int lt = 0; lt < 2; ++lt)
        bfrag[lt] = *(const bf16x8*)&xnT[32*wl + 16*lt + l15][kst*32 + 8*u];
#pragma unroll
      for (int ct = 0; ct < 4; ++ct){
        bf16x8 af = *(const bf16x8*)(W + (size_t)(64*wc + 16*ct + l15)*C_D + kst*32 + 8*u);
#pragma unroll
        for (int lt = 0; lt < 2; ++lt)
          acc[ct][lt] = __builtin_amdgcn_mfma_f32_16x16x32_bf16(af, bfrag[lt], acc[ct][lt], 0, 0, 0);
      }
    }

    if (wi < 2){
      float qs = (wi == 0) ? QSCALE : 1.0f;
      __syncthreads();   // prior projection's store phase done reading qbuf
#pragma unroll
      for (int ct = 0; ct < 4; ++ct){
        float bias[4];
#pragma unroll
        for (int r = 0; r < 4; ++r) bias[r] = Bv[64*wc + 16*ct + 4*u + r];
#pragma unroll
        for (int lt = 0; lt < 2; ++lt){
          float v0 = (acc[ct][lt][0] + bias[0]) * qs;
          float v1 = (acc[ct][lt][1] + bias[1]) * qs;
          float v2 = (acc[ct][lt][2] + bias[2]) * qs;
          float v3 = (acc[ct][lt][3] + bias[3]) * qs;
          int row = 32*wl + 16*lt + l15;
          int col = 64*wc + 16*ct + 4*u;
          *(unsigned int*)&qbuf[row][col]   = pk2(v0, v1);
          *(unsigned int*)&qbuf[row][col+2] = pk2(v2, v3);
        }
      }
      __syncthreads();   // qbuf writes visible
      {
        int l = t >> 2, ch = t & 3;
        unsigned short* dst = ((wi == 0) ? q_ws : k_ws) + (size_t)(n*L_D + l0 + l)*C_D + ch*32;
#pragma unroll
        for (int i = 0; i < 4; ++i)
          *(uint4*)(dst + i*8) = *(const uint4*)&qbuf[l][ch*32 + i*8];
      }
    } else {
      // v: store to [N][C][L] with within-16 m-index bits 2<->3 swapped
      int p16 = (l15 & 3) | ((l15 & 4) << 1) | ((l15 & 8) >> 1);
#pragma unroll
      for (int ct = 0; ct < 4; ++ct){
        float bias[4];
#pragma unroll
        for (int r = 0; r < 4; ++r) bias[r] = Bv[64*wc + 16*ct + 4*u + r];
#pragma unroll
        for (int lt = 0; lt < 2; ++lt)
#pragma unroll
          for (int r = 0; r < 4; ++r){
            int co = 64*wc + 16*ct + 4*u + r;
            v_ws[(size_t)(n*C_D + co)*L_D + l0 + 32*wl + 16*lt + p16] =
                f2bf(acc[ct][lt][r] + bias[r]);
          }
      }
    }
  }
}

// ---------------- kernel 3: flash attention + fused combine tail ------------
// grid 256 = N*16*SPLIT; block 512 (8 waves, 1 block/CU, 128KB LDS, 4-deep
// K/V buffers). Main loop = R7 config (best measured). Tail: po/md write ->
// release + flags[key]++ -> spin to 4 -> combine own 64-l quarter.
#define STEPBODY(STEP, SIN0, SIN1, SOUT0, SOUT1, DOQK)                           \
  {                                                                              \
    const int step_ = (STEP);                                                    \
    int pfi = step_ + 2; if (pfi > FSTEPS-1) pfi = FSTEPS-1;                     \
    int pbb = (step_ + 2) & 3;                                                   \
    {                                                                            \
      char* kN = shmem + (pbb << 14);                                            \
      char* vN = shmem + 65536 + (pbb << 14);                                    \
      gll16(kg[0] + (size_t)pfi*KVB*C_D, kN + ldof[0]);                          \
      gll16(kg[1] + (size_t)pfi*KVB*C_D, kN + ldof[1]);                          \
      gll16(vg[0] + pfi*KVB, vN + ldof[0]);                                      \
      gll16(vg[1] + pfi*KVB, vN + ldof[1]);                                      \
    }                                                                            \
    char* kB = shmem + ((step_ & 3) << 14);                                      \
    char* vP = shmem + 65536 + (((step_ - 1) & 3) << 14);                        \
    const bool doQK = (DOQK);                                                    \
    float p0[16], p1[16];                                                        \
    union Wu { unsigned int u[8]; bf16x8 h[2]; } Wm0, Wm1;                       \
    __builtin_amdgcn_s_setprio(1);                                               \
    /* QK chain mt=0 interleaved with exp2(SIN0) */                              \
    if (doQK){                                                                   \
      bf16x8 afr[8];                                                             \
      _Pragma("unroll")                                                          \
      for (int k = 0; k < 8; ++k)                                                \
        afr[k] = *(const bf16x8*)(kB + l31*256 +                                 \
                   ((32*k + 16*hi) ^ ((l31 & 15) << 4)));                        \
      SOUT0 = zz16;                                                              \
      _Pragma("unroll")                                                          \
      for (int k = 0; k < 8; ++k){                                               \
        SOUT0 = __builtin_amdgcn_mfma_f32_32x32x16_bf16(afr[k], qf[k], SOUT0, 0, 0, 0); \
        p0[2*k]   = exp2a(SIN0[2*k]   - FIXM);                                   \
        p0[2*k+1] = exp2a(SIN0[2*k+1] - FIXM);                                   \
      }                                                                          \
    } else {                                                                     \
      _Pragma("unroll")                                                          \
      for (int r = 0; r < 16; ++r) p0[r] = exp2a(SIN0[r] - FIXM);                \
    }                                                                            \
    /* QK chain mt=1 interleaved with pk2(p0) */                                 \
    if (doQK){                                                                   \
      bf16x8 afr[8];                                                             \
      _Pragma("unroll")                                                          \
      for (int k = 0; k < 8; ++k)                                                \
        afr[k] = *(const bf16x8*)(kB + (32 + l31)*256 +                          \
                   ((32*k + 16*hi) ^ ((l31 & 15) << 4)));                        \
      SOUT1 = zz16;                                                              \
      _Pragma("unroll")                                                          \
      for (int k = 0; k < 8; ++k){                                               \
        SOUT1 = __builtin_amdgcn_mfma_f32_32x32x16_bf16(afr[k], qf[k], SOUT1, 0, 0, 0); \
        Wm0.u[k] = pk2(p0[2*k], p0[2*k+1]);                                      \
      }                                                                          \
    } else {                                                                     \
      _Pragma("unroll")                                                          \
      for (int k = 0; k < 8; ++k) Wm0.u[k] = pk2(p0[2*k], p0[2*k+1]);            \
    }                                                                            \
    rsum += (((p0[0]+p0[1])+(p0[2]+p0[3])) + ((p0[4]+p0[5])+(p0[6]+p0[7])))      \
          + (((p0[8]+p0[9])+(p0[10]+p0[11])) + ((p0[12]+p0[13])+(p0[14]+p0[15])));\
    /* PV sl=0,1 (Wm0) interleaved with exp2(SIN1) */                            \
    _Pragma("unroll")                                                            \
    for (int sl = 0; sl < 2; ++sl){                                              \
      bf16x8 pfv = Wm0.h[sl];                                                    \
      bf16x8 vfr[4];                                                             \
      _Pragma("unroll")                                                          \
      for (int ct = 0; ct < 4; ++ct){                                            \
        int c = 32*ct + l31, vrow = c & 63;                                      \
        int lb = ((c >> 6) << 7) + 32*sl + 16*hi;                                \
        vfr[ct] = *(const bf16x8*)(vP + vrow*256 + (lb ^ ((vrow & 15) << 4)));   \
      }                                                                          \
      _Pragma("unroll")                                                          \
      for (int ct = 0; ct < 4; ++ct){                                            \
        accO[ct] = __builtin_amdgcn_mfma_f32_32x32x16_bf16(vfr[ct], pfv, accO[ct], 0, 0, 0); \
        p1[8*sl + 2*ct]     = exp2a(SIN1[8*sl + 2*ct]     - FIXM);               \
        p1[8*sl + 2*ct + 1] = exp2a(SIN1[8*sl + 2*ct + 1] - FIXM);               \
      }                                                                          \
    }                                                                            \
    _Pragma("unroll")                                                            \
    for (int k = 0; k < 8; ++k) Wm1.u[k] = pk2(p1[2*k], p1[2*k+1]);              \
    rsum += (((p1[0]+p1[1])+(p1[2]+p1[3])) + ((p1[4]+p1[5])+(p1[6]+p1[7])))      \
          + (((p1[8]+p1[9])+(p1[10]+p1[11])) + ((p1[12]+p1[13])+(p1[14]+p1[15])));\
    /* PV sl=2,3 (Wm1) */                                                        \
    _Pragma("unroll")                                                            \
    for (int sl = 2; sl < 4; ++sl){                                              \
      bf16x8 pfv = Wm1.h[sl & 1];                                                \
      bf16x8 vfr[4];                                                             \
      _Pragma("unroll")                                                          \
      for (int ct = 0; ct < 4; ++ct){                                            \
        int c = 32*ct + l31, vrow = c & 63;                                      \
        int lb = ((c >> 6) << 7) + 32*sl + 16*hi;                                \
        vfr[ct] = *(const bf16x8*)(vP + vrow*256 + (lb ^ ((vrow & 15) << 4)));   \
      }                                                                          \
      _Pragma("unroll")                                                          \
      for (int ct = 0; ct < 4; ++ct)                                             \
        accO[ct] = __builtin_amdgcn_mfma_f32_32x32x16_bf16(vfr[ct], pfv, accO[ct], 0, 0, 0); \
    }                                                                            \
    __builtin_amdgcn_s_setprio(0);                                               \
    asm volatile("s_waitcnt vmcnt(4)" ::: "memory");                             \
    __builtin_amdgcn_s_barrier();                                                \
    asm volatile("" ::: "memory");                                               \
  }

__global__ __launch_bounds__(512, 2) void flash_split_k(
    const unsigned short* __restrict__ q_ws, const unsigned short* __restrict__ k_ws,
    const unsigned short* __restrict__ v_ws,
    unsigned short* __restrict__ po_ws, float* __restrict__ md_ws,
    const float* __restrict__ x, const unsigned short* __restrict__ wo_bf,
    const float* __restrict__ bo, float* __restrict__ out,
    unsigned int* __restrict__ flags)
{
  __shared__ __align__(16) char shmem[131072];
  // K bufs @ (b<<14), b=0..3: 64 rows(m) x 256B(c), swz (row&15)<<4
  // V bufs @ 65536+(b<<14): 64 rows x 256B; row=c&63, byte=(c>>6)*128+2*mloc

  int t = threadIdx.x;
  int phys = blockIdx.x;
  int xcd = phys & 7, j = phys >> 3;
  int pair = xcd*8 + (j & 7);
  int s = j >> 3;
  int n = pair >> 4, lt256 = pair & 15;
  int l0 = lt256 * 256;
  int m_base = s * (L_D / SPLIT);
  int w = t >> 6, lane = t & 63, hi = lane >> 5, l31 = lane & 31;
  int lr = lane >> 4, ls = lane & 15;

  bf16x8 qf[8];
  {
    const unsigned short* qrow = q_ws + ((size_t)(n*L_D + l0 + 32*w + l31))*C_D;
#pragma unroll
    for (int kst = 0; kst < 8; ++kst)
      qf[kst] = *(const bf16x8*)(qrow + 16*kst + 8*hi);
  }

  f32x16 zz16;
#pragma unroll
  for (int i = 0; i < 16; ++i) zz16[i] = 0.f;
  f32x16 accO[4];
#pragma unroll
  for (int ct = 0; ct < 4; ++ct) accO[ct] = zz16;
  float rsum = 0.f;

  const unsigned short* kg[2];
  const unsigned short* vg[2];
  int ldof[2];
#pragma unroll
  for (int i = 0; i < 2; ++i){
    int row = 8*w + 4*i + lr;
    int ub = (ls << 4) ^ ((row & 15) << 4);
    kg[i] = k_ws + ((size_t)(n*L_D + m_base + row))*C_D + (ub >> 1);
    int c    = row + ((ub >> 7) << 6);
    int mloc = (ub & 127) >> 1;
    vg[i] = v_ws + ((size_t)(n*C_D + c))*L_D + m_base + mloc;
    ldof[i] = (8*w + 4*i)*256;
  }

  // prologue: stage tiles 0,1,2 (12 loads); wait so tiles 0,1 landed
#pragma unroll
  for (int pre = 0; pre < 3; ++pre){
    char* kD = shmem + (pre << 14);
    char* vD = shmem + 65536 + (pre << 14);
    gll16(kg[0] + (size_t)pre*KVB*C_D, kD + ldof[0]);
    gll16(kg[1] + (size_t)pre*KVB*C_D, kD + ldof[1]);
    gll16(vg[0] + pre*KVB, vD + ldof[0]);
    gll16(vg[1] + pre*KVB, vD + ldof[1]);
  }
  asm volatile("s_waitcnt vmcnt(4)" ::: "memory");
  __builtin_amdgcn_s_barrier();
  asm volatile("" ::: "memory");

  // prologue: QK(0) -> sA from buffer 0
  f32x16 sA0, sA1, sB0, sB1;
  {
    __builtin_amdgcn_s_setprio(1);
    sA0 = zz16; sA1 = zz16;
    bf16x8 afr[8];
#pragma unroll
    for (int k = 0; k < 8; ++k)
      afr[k] = *(const bf16x8*)(shmem + l31*256 + ((32*k + 16*hi) ^ ((l31 & 15) << 4)));
#pragma unroll
    for (int k = 0; k < 8; ++k)
      sA0 = __builtin_amdgcn_mfma_f32_32x32x16_bf16(afr[k], qf[k], sA0, 0, 0, 0);
#pragma unroll
    for (int k = 0; k < 8; ++k)
      afr[k] = *(const bf16x8*)(shmem + (32 + l31)*256 + ((32*k + 16*hi) ^ ((l31 & 15) << 4)));
#pragma unroll
    for (int k = 0; k < 8; ++k)
      sA1 = __builtin_amdgcn_mfma_f32_32x32x16_bf16(afr[k], qf[k], sA1, 0, 0, 0);
    __builtin_amdgcn_s_setprio(0);
  }

  // main loop: steps 1..16; step s does softmax(s-1)+PV(s-1), QK(s) if s<16
  for (int e = 1; e < 17; e += 2){
    STEPBODY(e,     sA0, sA1, sB0, sB1, true)
    STEPBODY(e + 1, sB0, sB1, sA0, sA1, (e + 1 < FSTEPS))
  }

  // drain remaining (clamped) prefetches before reusing shmem
  asm volatile("s_waitcnt vmcnt(0)" ::: "memory");
  __builtin_amdgcn_s_barrier();
  asm volatile("" ::: "memory");

  rsum += __shfl_xor(rsum, 32);

  // epilogue: transpose accO into LDS as [l][c] bf16 (swizzled), coalesced po write
  char* tB = shmem;
  {
    int lloc = 32*w + l31;
    int tsw = (lloc & 15) << 4;
    char* tr = tB + (size_t)lloc*256;
#pragma unroll
    for (int ct = 0; ct < 4; ++ct)
#pragma unroll
      for (int q = 0; q < 4; ++q){
        int cb2 = 64*ct + 16*q + 8*hi;
        *(unsigned int*)(tr + ((cb2    ) ^ tsw)) = pk2(accO[ct][4*q+0], accO[ct][4*q+1]);
        *(unsigned int*)(tr + ((cb2 + 4) ^ tsw)) = pk2(accO[ct][4*q+2], accO[ct][4*q+3]);
      }
  }
  __syncthreads();
  {
    int row2 = t >> 1, hf2 = t & 1;
    int tile = row2 >> 7, lrow = row2 & 127;
    size_t pb = ((size_t)((n*32 + 2*lt256 + tile)*SPLIT + s)) * (size_t)(128*128);
    unsigned short* dst = po_ws + pb + (size_t)lrow*128 + hf2*64;
    const char* srcr = tB + row2*256;
    int sw2 = (row2 & 15) << 4;
#pragma unroll
    for (int i = 0; i < 8; ++i)
      *(uint4*)(dst + 8*i) = *(const uint4*)(srcr + ((hf2*128 + 16*i) ^ sw2));
  }
  if (lane < 32){
    int lg = 32*w + lane;
    int tile2 = lg >> 7, lrow2 = lg & 127;
    size_t mb2 = ((size_t)((n*32 + 2*lt256 + tile2)*SPLIT + s)) * 128;
    md_ws[mb2 + lrow2] = rsum;
  }

  // ---- fused combine: sync the 4 split blocks of this key, then combine ----
  __syncthreads();   // all po/md stores issued + retired (vmcnt drained)
  if (t == 0){
    __threadfence(); // agent-scope release: write back L2 so siblings see po/md
    __hip_atomic_fetch_add(&flags[pair], 1u, __ATOMIC_RELEASE, __HIP_MEMORY_SCOPE_AGENT);
    while (__hip_atomic_load(&flags[pair], __ATOMIC_ACQUIRE, __HIP_MEMORY_SCOPE_AGENT) < 4u) {}
  }
  __syncthreads();

  {
    // this block combines the 64-l quarter equal to its split index s
    int lt64 = lt256*4 + s;
    int f2 = lt64 >> 1, loff = (lt64 & 1)*64, l0c = lt64*64;
    size_t pbase = ((size_t)((n*32 + f2)*SPLIT)) * (size_t)(128*128);
    size_t mbase = ((size_t)((n*32 + f2)*SPLIT)) * 128;
    char* aB = shmem;   // 64 rows(l) x 256B(c), swizzled (l&7)<<4

    {
      int l = t >> 3, q8 = t & 7;
      float Dg = 0.f;
#pragma unroll
      for (int s2 = 0; s2 < SPLIT; ++s2)
        Dg += md_ws[mbase + s2*128 + loff + l];
      float inv = 1.0f / Dg;

      float a[16];
#pragma unroll
      for (int i = 0; i < 16; ++i) a[i] = 0.f;
#pragma unroll
      for (int s2 = 0; s2 < SPLIT; ++s2){
        const uint4* p = (const uint4*)(po_ws + pbase + (size_t)s2*(128*128)
                                        + (size_t)(loff + l)*128 + q8*16);
#pragma unroll
        for (int i = 0; i < 2; ++i){
          uint4 uv = p[i];
          unsigned int uu[4] = {uv.x, uv.y, uv.z, uv.w};
#pragma unroll
          for (int j2 = 0; j2 < 4; ++j2){
            a[8*i + 2*j2]     += bf2f((unsigned short)(uu[j2] & 0xffffu));
            a[8*i + 2*j2 + 1] += bf2f((unsigned short)(uu[j2] >> 16));
          }
        }
      }
      char* ar = aB + l*256;
      int asw = (l & 7) << 4;
#pragma unroll
      for (int i = 0; i < 8; ++i){
        int cb = q8*32 + 4*i;
        *(unsigned int*)(ar + (cb ^ asw)) = pk2(a[2*i]*inv, a[2*i+1]*inv);
      }
    }
    __syncthreads();

    {
      // out = x + wo*attn + bo : wave w does 32 o-channels x 32 l
      int ow = w & 3, lh2 = w >> 2;
      f32x16 acc;
#pragma unroll
      for (int i = 0; i < 16; ++i) acc[i] = 0.f;
#pragma unroll
      for (int kst = 0; kst < 8; ++kst){
        int row = 32*lh2 + l31;
        bf16x8 bfg = *(const bf16x8*)(aB + row*256 + ((32*kst + 16*hi) ^ ((row & 7) << 4)));
        bf16x8 af = *(const bf16x8*)(wo_bf + (size_t)(32*ow + l31)*C_D + 16*kst + 8*hi);
        acc = __builtin_amdgcn_mfma_f32_32x32x16_bf16(af, bfg, acc, 0, 0, 0);
      }
#pragma unroll
      for (int r = 0; r < 16; ++r){
        int o = 32*ow + (r & 3) + 8*(r >> 2) + 4*hi;
        size_t idx = (size_t)(n*C_D + o)*L_D + l0c + 32*lh2 + l31;
        out[idx] = x[idx] + bo[o] + acc[r];
      }
    }
  }
}

extern "C" void kernel_launch(void* const* d_in, const int* in_sizes, int n_in,
                              void* d_out, int out_size, void* d_ws, size_t ws_size,
                              hipStream_t stream) {
  const float* x     = (const float*)d_in[0];
  const float* gamma = (const float*)d_in[1];
  const float* beta  = (const float*)d_in[2];
  const float* wq    = (const float*)d_in[3];
  const float* bq    = (const float*)d_in[4];
  const float* wk    = (const float*)d_in[5];
  const float* bk    = (const float*)d_in[6];
  const float* wv    = (const float*)d_in[7];
  const float* bv    = (const float*)d_in[8];
  const float* wo    = (const float*)d_in[9];
  const float* bo    = (const float*)d_in[10];
  float* out = (float*)d_out;

  char* ws = (char*)d_ws;
  float* stats          = (float*)ws;
  unsigned short* q_ws  = (unsigned short*)(ws + 4096);
  unsigned short* k_ws  = q_ws + (size_t)N_B * L_D * C_D;
  unsigned short* v_ws  = k_ws + (size_t)N_B * L_D * C_D;
  unsigned short* po_ws = v_ws + (size_t)N_B * L_D * C_D;
  float* md_ws          = (float*)(po_ws + (size_t)N_B * 32 * SPLIT * 128 * 128);
  unsigned short* wbf   = (unsigned short*)(md_ws + (size_t)N_B * 32 * SPLIT * 128);
  unsigned int* flags   = (unsigned int*)(wbf + 4*16384);

  gnw_k<<<192, 256, 0, stream>>>(x, stats, wq, wk, wv, wo, wbf, flags);
  qkv_k<<<256, 256, 0, stream>>>(x, stats, gamma, beta, wbf, bq, bk, bv,
                                 q_ws, k_ws, v_ws);
  flash_split_k<<<256, 512, 0, stream>>>(q_ws, k_ws, v_ws, po_ws, md_ws,
                                         x, wbf + 3*16384, bo, out, flags);
}

// Round 12
// 72.666 us; speedup vs baseline: 1.2265x; 1.2265x over previous
//
#include <hip/hip_runtime.h>
#include <hip/hip_bf16.h>

// AttentionBlock: N=4, C=128, H=W=64 (L=4096), 32 groups.
// Fixed-softmax-max scheme: scores S*log2e ~ N(0,~1.4^2); max << FIXM=16.
// P = exp2(S-16); partials additive across splits.
// ws: [0,4KB) spare; q_ws [N][L][C] bf16; k_ws [N][L][C] bf16;
// v_ws [N][C][L] bf16 (m bit2<->bit3 permuted per 16-group);
// po_ws [N][32][SPLIT][128][128] bf16; md_ws f32; wbf [4][128][128] bf16;
// xn_ws [N][C][L] bf16 (GN-normalized x, written by gnw).
//
// LESSONS: (R3/R4) launch_bounds min-waves=4 -> 64-VGPR cap -> spill disaster.
// (R0-R9) flash schedule space exhausted: 1-bar/step 45.5, counted vmcnt 45.7,
// intra-wave fold 43.9 (BEST = 783 TF ~ plain-HIP structural plateau),
// 8-phase 47.4, wave-split 48.7. MFMA/VALU/LDS pipes serialize per step
// across all schedules. (R10) qkv-merge + combine-split: 72.7 (best total).
// (R11) fused combine-with-spin: REGRESSION to 89 (cross-XCD spin serializes).
// R12: revert to R10 + gnw emits xn bf16 (normalize in-register after stats),
// qkv reads bf16 xn (half the bytes, no GN math).

#define N_B 4
#define C_D 128
#define L_D 4096
#define SPLIT 4
#define KVB 64
#define FSTEPS ((L_D/SPLIT)/KVB)   // 16
#define QSCALE (0.08838834764831845f * 1.4426950408889634f)
#define FIXM 16.0f

using f32x4  = __attribute__((ext_vector_type(4))) float;
using f32x16 = __attribute__((ext_vector_type(16))) float;
using bf16x8 = __attribute__((ext_vector_type(8))) short;

static __device__ __forceinline__ unsigned short f2bf(float f){
  return (unsigned short)((__builtin_bit_cast(unsigned int, f) + 0x8000u) >> 16);
}
static __device__ __forceinline__ float bf2f(unsigned short u){
  unsigned int x = ((unsigned int)u) << 16;
  return __builtin_bit_cast(float, x);
}
static __device__ __forceinline__ unsigned int pk2(float a, float b){
  unsigned int ua = __builtin_bit_cast(unsigned int, a) + 0x8000u;
  unsigned int ub = __builtin_bit_cast(unsigned int, b) + 0x8000u;
  return __builtin_amdgcn_perm(ub, ua, 0x07060302u);
}
static __device__ __forceinline__ float exp2a(float x){
  float r; asm("v_exp_f32 %0, %1" : "=v"(r) : "v"(x)); return r;
}
static __device__ __forceinline__ void gll16(const void* g, void* l){
  __builtin_amdgcn_global_load_lds(
      (const __attribute__((address_space(1))) unsigned int*)g,
      (__attribute__((address_space(3))) unsigned int*)l, 16, 0, 0);
}

// ---------------- kernel 1: GroupNorm (stats + normalize -> xn bf16) + w->bf16
// blocks 0-127: one block per (n,group); x slice held in registers across the
// stats reduction, then normalized+gamma/beta applied and stored as bf16 xn.
// blocks 128-191: weight fp32->bf16 conversion.
__global__ __launch_bounds__(256) void gnw_k(
    const float* __restrict__ x,
    const float* __restrict__ gamma, const float* __restrict__ beta,
    const float* __restrict__ wq, const float* __restrict__ wk,
    const float* __restrict__ wv, const float* __restrict__ wo,
    unsigned short* __restrict__ wbf, unsigned short* __restrict__ xn)
{
  int b = blockIdx.x, t = threadIdx.x;
  if (b >= 128){
    int b2 = b - 128;
    int mat = b2 >> 4;
    const float* src = (mat == 0) ? wq : (mat == 1) ? wk : (mat == 2) ? wv : wo;
    int off = (b2 & 15) * 1024 + t * 4;
    float4 v = *(const float4*)(src + off);
    *(uint2*)(wbf + mat*16384 + off) = make_uint2(pk2(v.x, v.y), pk2(v.z, v.w));
    return;
  }
  // block b covers global channels [4b, 4b+4) = (n = b>>5, group = b&31)
  const float4* p = (const float4*)(x + (size_t)b * (4 * L_D));
  float4 vbuf[16];
  float s = 0.f, ss = 0.f;
#pragma unroll
  for (int i = 0; i < 16; ++i){
    float4 v = p[t + i*256];
    vbuf[i] = v;
    s  += v.x + v.y + v.z + v.w;
    ss += v.x*v.x + v.y*v.y + v.z*v.z + v.w*v.w;
  }
#pragma unroll
  for (int off = 32; off > 0; off >>= 1){
    s  += __shfl_down(s, off);
    ss += __shfl_down(ss, off);
  }
  __shared__ float rs4[4], rss4[4];
  if ((t & 63) == 0){ rs4[t>>6] = s; rss4[t>>6] = ss; }
  __syncthreads();
  // every thread computes mean/rstd (cheap; avoids a broadcast round)
  s  = rs4[0]+rs4[1]+rs4[2]+rs4[3];
  ss = rss4[0]+rss4[1]+rss4[2]+rss4[3];
  float mean = s * (1.f/16384.f);
  float var  = ss * (1.f/16384.f) - mean*mean;
  if (var < 0.f) var = 0.f;
  float rstd = rsqrtf(var + 1e-6f);

  int cb = (b & 31) * 4;        // local channel base within [0,128)
  float scv[4], bsv[4];
#pragma unroll
  for (int ch = 0; ch < 4; ++ch){
    scv[ch] = rstd * gamma[cb + ch];
    bsv[ch] = beta[cb + ch] - mean * scv[ch];
  }
  unsigned short* xo = xn + (size_t)b * (4 * L_D);
#pragma unroll
  for (int i = 0; i < 16; ++i){
    int j  = t + i*256;
    int ch = j >> 10;           // 1024 float4 per channel
    float4 v = vbuf[i];
    float sc = scv[ch], bs = bsv[ch];
    float v0 = v.x*sc + bs, v1 = v.y*sc + bs;
    float v2 = v.z*sc + bs, v3 = v.w*sc + bs;
    *(uint2*)(xo + (size_t)j*4) = make_uint2(pk2(v0, v1), pk2(v2, v3));
  }
}

// ---------------- kernel 2: ALL THREE projections per block (from bf16 xn) --
// grid 256 (one block per 64-l x-tile): stage xnT once, loop wi=0..2.
__global__ __launch_bounds__(256) void qkv_k(
    const unsigned short* __restrict__ xn,
    const unsigned short* __restrict__ wbf,
    const float* __restrict__ bq, const float* __restrict__ bk,
    const float* __restrict__ bv,
    unsigned short* __restrict__ q_ws, unsigned short* __restrict__ k_ws,
    unsigned short* __restrict__ v_ws)
{
  __shared__ unsigned short xnT[64][136];
  __shared__ unsigned short qbuf[64][136];

  int t = threadIdx.x, b = blockIdx.x;
  int n = b >> 6, l0 = (b & 63) * 64;

  { // stage xnT (transpose of the bf16 xn slice) once for this l-tile
    int l = t & 63, cq = t >> 6;
    const unsigned short* xr = xn + ((size_t)n*C_D)*L_D + l0 + l;
#pragma unroll
    for (int it = 0; it < 8; ++it){
      int c0 = cq*4 + it*16;
      unsigned int u0 = xr[(size_t)(c0+0)*L_D];
      unsigned int u1 = xr[(size_t)(c0+1)*L_D];
      unsigned int u2 = xr[(size_t)(c0+2)*L_D];
      unsigned int u3 = xr[(size_t)(c0+3)*L_D];
      *(unsigned int*)&xnT[l][c0]   = u0 | (u1 << 16);
      *(unsigned int*)&xnT[l][c0+2] = u2 | (u3 << 16);
    }
  }
  __syncthreads();

  int w = t >> 6, lane = t & 63, u = lane >> 4, l15 = lane & 15;
  int wc = w >> 1, wl = w & 1;
  f32x4 zz = {0.f,0.f,0.f,0.f};

  for (int wi = 0; wi < 3; ++wi){
    const unsigned short* W = wbf + wi*16384;
    const float* Bv = (wi == 0) ? bq : (wi == 1) ? bk : bv;

    f32x4 acc[4][2];
#pragma unroll
    for (int ct = 0; ct < 4; ++ct)
#pragma unroll
      for (int lt = 0; lt < 2; ++lt) acc[ct][lt] = zz;

#pragma unroll
    for (int kst = 0; kst < 4; ++kst){
      bf16x8 bfrag[2];
#pragma unroll
      for (int lt = 0; lt < 2; ++lt)
        bfrag[lt] = *(const bf16x8*)&xnT[32*wl + 16*lt + l15][kst*32 + 8*u];
#pragma unroll
      for (int ct = 0; ct < 4; ++ct){
        bf16x8 af = *(const bf16x8*)(W + (size_t)(64*wc + 16*ct + l15)*C_D + kst*32 + 8*u);
#pragma unroll
        for (int lt = 0; lt < 2; ++lt)
          acc[ct][lt] = __builtin_amdgcn_mfma_f32_16x16x32_bf16(af, bfrag[lt], acc[ct][lt], 0, 0, 0);
      }
    }

    if (wi < 2){
      float qs = (wi == 0) ? QSCALE : 1.0f;
      __syncthreads();   // prior projection's store phase done reading qbuf
#pragma unroll
      for (int ct = 0; ct < 4; ++ct){
        float bias[4];
#pragma unroll
        for (int r = 0; r < 4; ++r) bias[r] = Bv[64*wc + 16*ct + 4*u + r];
#pragma unroll
        for (int lt = 0; lt < 2; ++lt){
          float v0 = (acc[ct][lt][0] + bias[0]) * qs;
          float v1 = (acc[ct][lt][1] + bias[1]) * qs;
          float v2 = (acc[ct][lt][2] + bias[2]) * qs;
          float v3 = (acc[ct][lt][3] + bias[3]) * qs;
          int row = 32*wl + 16*lt + l15;
          int col = 64*wc + 16*ct + 4*u;
          *(unsigned int*)&qbuf[row][col]   = pk2(v0, v1);
          *(unsigned int*)&qbuf[row][col+2] = pk2(v2, v3);
        }
      }
      __syncthreads();   // qbuf writes visible
      {
        int l = t >> 2, ch = t & 3;
        unsigned short* dst = ((wi == 0) ? q_ws : k_ws) + (size_t)(n*L_D + l0 + l)*C_D + ch*32;
#pragma unroll
        for (int i = 0; i < 4; ++i)
          *(uint4*)(dst + i*8) = *(const uint4*)&qbuf[l][ch*32 + i*8];
      }
    } else {
      // v: store to [N][C][L] with within-16 m-index bits 2<->3 swapped
      int p16 = (l15 & 3) | ((l15 & 4) << 1) | ((l15 & 8) >> 1);
#pragma unroll
      for (int ct = 0; ct < 4; ++ct){
        float bias[4];
#pragma unroll
        for (int r = 0; r < 4; ++r) bias[r] = Bv[64*wc + 16*ct + 4*u + r];
#pragma unroll
        for (int lt = 0; lt < 2; ++lt)
#pragma unroll
          for (int r = 0; r < 4; ++r){
            int co = 64*wc + 16*ct + 4*u + r;
            v_ws[(size_t)(n*C_D + co)*L_D + l0 + 32*wl + 16*lt + p16] =
                f2bf(acc[ct][lt][r] + bias[r]);
          }
      }
    }
  }
}

// ---------------- kernel 3: flash attention (R7 config: best measured) ------
// grid 256 = N*16*SPLIT; block 512 (8 waves, 1 block/CU, 128KB LDS, 4-deep
// K/V buffers). One-step-behind pipeline: step s does QK(s) with softmax(s-1)
// exp2/pk2 folded into the MFMA latency slots, then PV(s-1) (sl=0,1 overlap
// the second softmax half). Prefetch distance 2; s_waitcnt vmcnt(4) + raw
// s_barrier per step — never drain in the loop.
#define STEPBODY(STEP, SIN0, SIN1, SOUT0, SOUT1, DOQK)                           \
  {                                                                              \
    const int step_ = (STEP);                                                    \
    int pfi = step_ + 2; if (pfi > FSTEPS-1) pfi = FSTEPS-1;                     \
    int pbb = (step_ + 2) & 3;                                                   \
    {                                                                            \
      char* kN = shmem + (pbb << 14);                                            \
      char* vN = shmem + 65536 + (pbb << 14);                                    \
      gll16(kg[0] + (size_t)pfi*KVB*C_D, kN + ldof[0]);                          \
      gll16(kg[1] + (size_t)pfi*KVB*C_D, kN + ldof[1]);                          \
      gll16(vg[0] + pfi*KVB, vN + ldof[0]);                                      \
      gll16(vg[1] + pfi*KVB, vN + ldof[1]);                                      \
    }                                                                            \
    char* kB = shmem + ((step_ & 3) << 14);                                      \
    char* vP = shmem + 65536 + (((step_ - 1) & 3) << 14);                        \
    const bool doQK = (DOQK);                                                    \
    float p0[16], p1[16];                                                        \
    union Wu { unsigned int u[8]; bf16x8 h[2]; } Wm0, Wm1;                       \
    __builtin_amdgcn_s_setprio(1);                                               \
    /* QK chain mt=0 interleaved with exp2(SIN0) */                              \
    if (doQK){                                                                   \
      bf16x8 afr[8];                                                             \
      _Pragma("unroll")                                                          \
      for (int k = 0; k < 8; ++k)                                                \
        afr[k] = *(const bf16x8*)(kB + l31*256 +                                 \
                   ((32*k + 16*hi) ^ ((l31 & 15) << 4)));                        \
      SOUT0 = zz16;                                                              \
      _Pragma("unroll")                                                          \
      for (int k = 0; k < 8; ++k){                                               \
        SOUT0 = __builtin_amdgcn_mfma_f32_32x32x16_bf16(afr[k], qf[k], SOUT0, 0, 0, 0); \
        p0[2*k]   = exp2a(SIN0[2*k]   - FIXM);                                   \
        p0[2*k+1] = exp2a(SIN0[2*k+1] - FIXM);                                   \
      }                                                                          \
    } else {                                                                     \
      _Pragma("unroll")                                                          \
      for (int r = 0; r < 16; ++r) p0[r] = exp2a(SIN0[r] - FIXM);                \
    }                                                                            \
    /* QK chain mt=1 interleaved with pk2(p0) */                                 \
    if (doQK){                                                                   \
      bf16x8 afr[8];                                                             \
      _Pragma("unroll")                                                          \
      for (int k = 0; k < 8; ++k)                                                \
        afr[k] = *(const bf16x8*)(kB + (32 + l31)*256 +                          \
                   ((32*k + 16*hi) ^ ((l31 & 15) << 4)));                        \
      SOUT1 = zz16;                                                              \
      _Pragma("unroll")                                                          \
      for (int k = 0; k < 8; ++k){                                               \
        SOUT1 = __builtin_amdgcn_mfma_f32_32x32x16_bf16(afr[k], qf[k], SOUT1, 0, 0, 0); \
        Wm0.u[k] = pk2(p0[2*k], p0[2*k+1]);                                      \
      }                                                                          \
    } else {                                                                     \
      _Pragma("unroll")                                                          \
      for (int k = 0; k < 8; ++k) Wm0.u[k] = pk2(p0[2*k], p0[2*k+1]);            \
    }                                                                            \
    rsum += (((p0[0]+p0[1])+(p0[2]+p0[3])) + ((p0[4]+p0[5])+(p0[6]+p0[7])))      \
          + (((p0[8]+p0[9])+(p0[10]+p0[11])) + ((p0[12]+p0[13])+(p0[14]+p0[15])));\
    /* PV sl=0,1 (Wm0) interleaved with exp2(SIN1) */                            \
    _Pragma("unroll")                                                            \
    for (int sl = 0; sl < 2; ++sl){                                              \
      bf16x8 pfv = Wm0.h[sl];                                                    \
      bf16x8 vfr[4];                                                             \
      _Pragma("unroll")                                                          \
      for (int ct = 0; ct < 4; ++ct){                                            \
        int c = 32*ct + l31, vrow = c & 63;                                      \
        int lb = ((c >> 6) << 7) + 32*sl + 16*hi;                                \
        vfr[ct] = *(const bf16x8*)(vP + vrow*256 + (lb ^ ((vrow & 15) << 4)));   \
      }                                                                          \
      _Pragma("unroll")                                                          \
      for (int ct = 0; ct < 4; ++ct){                                            \
        accO[ct] = __builtin_amdgcn_mfma_f32_32x32x16_bf16(vfr[ct], pfv, accO[ct], 0, 0, 0); \
        p1[8*sl + 2*ct]     = exp2a(SIN1[8*sl + 2*ct]     - FIXM);               \
        p1[8*sl + 2*ct + 1] = exp2a(SIN1[8*sl + 2*ct + 1] - FIXM);               \
      }                                                                          \
    }                                                                            \
    _Pragma("unroll")                                                            \
    for (int k = 0; k < 8; ++k) Wm1.u[k] = pk2(p1[2*k], p1[2*k+1]);              \
    rsum += (((p1[0]+p1[1])+(p1[2]+p1[3])) + ((p1[4]+p1[5])+(p1[6]+p1[7])))      \
          + (((p1[8]+p1[9])+(p1[10]+p1[11])) + ((p1[12]+p1[13])+(p1[14]+p1[15])));\
    /* PV sl=2,3 (Wm1) */                                                        \
    _Pragma("unroll")                                                            \
    for (int sl = 2; sl < 4; ++sl){                                              \
      bf16x8 pfv = Wm1.h[sl & 1];                                                \
      bf16x8 vfr[4];                                                             \
      _Pragma("unroll")                                                          \
      for (int ct = 0; ct < 4; ++ct){                                            \
        int c = 32*ct + l31, vrow = c & 63;                                      \
        int lb = ((c >> 6) << 7) + 32*sl + 16*hi;                                \
        vfr[ct] = *(const bf16x8*)(vP + vrow*256 + (lb ^ ((vrow & 15) << 4)));   \
      }                                                                          \
      _Pragma("unroll")                                                          \
      for (int ct = 0; ct < 4; ++ct)                                             \
        accO[ct] = __builtin_amdgcn_mfma_f32_32x32x16_bf16(vfr[ct], pfv, accO[ct], 0, 0, 0); \
    }                                                                            \
    __builtin_amdgcn_s_setprio(0);                                               \
    asm volatile("s_waitcnt vmcnt(4)" ::: "memory");                             \
    __builtin_amdgcn_s_barrier();                                                \
    asm volatile("" ::: "memory");                                               \
  }

__global__ __launch_bounds__(512, 2) void flash_split_k(
    const unsigned short* __restrict__ q_ws, const unsigned short* __restrict__ k_ws,
    const unsigned short* __restrict__ v_ws,
    unsigned short* __restrict__ po_ws, float* __restrict__ md_ws)
{
  __shared__ __align__(16) char shmem[131072];
  // K bufs @ (b<<14), b=0..3: 64 rows(m) x 256B(c), swz (row&15)<<4
  // V bufs @ 65536+(b<<14): 64 rows x 256B; row=c&63, byte=(c>>6)*128+2*mloc

  int t = threadIdx.x;
  int phys = blockIdx.x;
  int xcd = phys & 7, j = phys >> 3;
  int pair = xcd*8 + (j & 7);
  int s = j >> 3;
  int n = pair >> 4, lt256 = pair & 15;
  int l0 = lt256 * 256;
  int m_base = s * (L_D / SPLIT);
  int w = t >> 6, lane = t & 63, hi = lane >> 5, l31 = lane & 31;
  int lr = lane >> 4, ls = lane & 15;

  bf16x8 qf[8];
  {
    const unsigned short* qrow = q_ws + ((size_t)(n*L_D + l0 + 32*w + l31))*C_D;
#pragma unroll
    for (int kst = 0; kst < 8; ++kst)
      qf[kst] = *(const bf16x8*)(qrow + 16*kst + 8*hi);
  }

  f32x16 zz16;
#pragma unroll
  for (int i = 0; i < 16; ++i) zz16[i] = 0.f;
  f32x16 accO[4];
#pragma unroll
  for (int ct = 0; ct < 4; ++ct) accO[ct] = zz16;
  float rsum = 0.f;

  const unsigned short* kg[2];
  const unsigned short* vg[2];
  int ldof[2];
#pragma unroll
  for (int i = 0; i < 2; ++i){
    int row = 8*w + 4*i + lr;
    int ub = (ls << 4) ^ ((row & 15) << 4);
    kg[i] = k_ws + ((size_t)(n*L_D + m_base + row))*C_D + (ub >> 1);
    int c    = row + ((ub >> 7) << 6);
    int mloc = (ub & 127) >> 1;
    vg[i] = v_ws + ((size_t)(n*C_D + c))*L_D + m_base + mloc;
    ldof[i] = (8*w + 4*i)*256;
  }

  // prologue: stage tiles 0,1,2 (12 loads); wait so tiles 0,1 landed
#pragma unroll
  for (int pre = 0; pre < 3; ++pre){
    char* kD = shmem + (pre << 14);
    char* vD = shmem + 65536 + (pre << 14);
    gll16(kg[0] + (size_t)pre*KVB*C_D, kD + ldof[0]);
    gll16(kg[1] + (size_t)pre*KVB*C_D, kD + ldof[1]);
    gll16(vg[0] + pre*KVB, vD + ldof[0]);
    gll16(vg[1] + pre*KVB, vD + ldof[1]);
  }
  asm volatile("s_waitcnt vmcnt(4)" ::: "memory");
  __builtin_amdgcn_s_barrier();
  asm volatile("" ::: "memory");

  // prologue: QK(0) -> sA from buffer 0
  f32x16 sA0, sA1, sB0, sB1;
  {
    __builtin_amdgcn_s_setprio(1);
    sA0 = zz16; sA1 = zz16;
    bf16x8 afr[8];
#pragma unroll
    for (int k = 0; k < 8; ++k)
      afr[k] = *(const bf16x8*)(shmem + l31*256 + ((32*k + 16*hi) ^ ((l31 & 15) << 4)));
#pragma unroll
    for (int k = 0; k < 8; ++k)
      sA0 = __builtin_amdgcn_mfma_f32_32x32x16_bf16(afr[k], qf[k], sA0, 0, 0, 0);
#pragma unroll
    for (int k = 0; k < 8; ++k)
      afr[k] = *(const bf16x8*)(shmem + (32 + l31)*256 + ((32*k + 16*hi) ^ ((l31 & 15) << 4)));
#pragma unroll
    for (int k = 0; k < 8; ++k)
      sA1 = __builtin_amdgcn_mfma_f32_32x32x16_bf16(afr[k], qf[k], sA1, 0, 0, 0);
    __builtin_amdgcn_s_setprio(0);
  }

  // main loop: steps 1..16; step s does softmax(s-1)+PV(s-1), QK(s) if s<16
  for (int e = 1; e < 17; e += 2){
    STEPBODY(e,     sA0, sA1, sB0, sB1, true)
    STEPBODY(e + 1, sB0, sB1, sA0, sA1, (e + 1 < FSTEPS))
  }

  // drain remaining (clamped) prefetches before reusing shmem
  asm volatile("s_waitcnt vmcnt(0)" ::: "memory");
  __builtin_amdgcn_s_barrier();
  asm volatile("" ::: "memory");

  rsum += __shfl_xor(rsum, 32);

  // epilogue: transpose accO into LDS as [l][c] bf16 (swizzled), coalesced po write
  char* tB = shmem;
  {
    int lloc = 32*w + l31;
    int tsw = (lloc & 15) << 4;
    char* tr = tB + (size_t)lloc*256;
#pragma unroll
    for (int ct = 0; ct < 4; ++ct)
#pragma unroll
      for (int q = 0; q < 4; ++q){
        int cb2 = 64*ct + 16*q + 8*hi;
        *(unsigned int*)(tr + ((cb2    ) ^ tsw)) = pk2(accO[ct][4*q+0], accO[ct][4*q+1]);
        *(unsigned int*)(tr + ((cb2 + 4) ^ tsw)) = pk2(accO[ct][4*q+2], accO[ct][4*q+3]);
      }
  }
  __syncthreads();
  {
    int row2 = t >> 1, hf2 = t & 1;
    int tile = row2 >> 7, lrow = row2 & 127;
    size_t pb = ((size_t)((n*32 + 2*lt256 + tile)*SPLIT + s)) * (size_t)(128*128);
    unsigned short* dst = po_ws + pb + (size_t)lrow*128 + hf2*64;
    const char* srcr = tB + row2*256;
    int sw2 = (row2 & 15) << 4;
#pragma unroll
    for (int i = 0; i < 8; ++i)
      *(uint4*)(dst + 8*i) = *(const uint4*)(srcr + ((hf2*128 + 16*i) ^ sw2));
  }
  if (lane < 32){
    int lg = 32*w + lane;
    int tile2 = lg >> 7, lrow2 = lg & 127;
    size_t mb2 = ((size_t)((n*32 + 2*lt256 + tile2)*SPLIT + s)) * 128;
    md_ws[mb2 + lrow2] = rsum;
  }
}

// ---------------- kernel 4: combine partials + out-proj + residual ----------
// grid 512 (2 blocks/CU; XCD-aligned with flash's po writer); block 256
// (4 waves); 32-l tiles. Partials ADDITIVE: attn = (sum_s po_s)/(sum_s D_s).
__global__ __launch_bounds__(256) void combine_k(
    const unsigned short* __restrict__ po_ws, const float* __restrict__ md_ws,
    const float* __restrict__ x, const unsigned short* __restrict__ wo_bf,
    const float* __restrict__ bo, float* __restrict__ out)
{
  __shared__ __align__(16) char aB[8192];    // 32 rows(l) x 256B(c), swizzled

  int t = threadIdx.x, b = blockIdx.x;
  int xcd = b & 7, j = b >> 3;               // j in [0,64)
  int pair = xcd*8 + (j & 7);                // same (n,lt256) key as flash
  int eighth = j >> 3;                       // 32-l slice within the 256-l tile
  int n = pair >> 4, lt256 = pair & 15;
  int lt32 = lt256*8 + eighth;               // [0,128)
  int f = lt32 >> 2;                         // po 128-l tile
  int loff = (lt32 & 3) * 32;
  int l0 = lt32 * 32;
  size_t pbase = ((size_t)((n*32 + f)*SPLIT)) * (size_t)(128*128);
  size_t mbase = ((size_t)((n*32 + f)*SPLIT)) * 128;

  { // merge splits: thread covers (l = t>>3, 16-channel slice q8 = t&7)
    int l = t >> 3, q8 = t & 7;
    float Dg = 0.f;
#pragma unroll
    for (int s2 = 0; s2 < SPLIT; ++s2)
      Dg += md_ws[mbase + s2*128 + loff + l];
    float inv = 1.0f / Dg;

    float a[16];
#pragma unroll
    for (int i = 0; i < 16; ++i) a[i] = 0.f;
#pragma unroll
    for (int s2 = 0; s2 < SPLIT; ++s2){
      const uint4* p = (const uint4*)(po_ws + pbase + (size_t)s2*(128*128)
                                      + (size_t)(loff + l)*128 + q8*16);
#pragma unroll
      for (int i = 0; i < 2; ++i){
        uint4 uv = p[i];
        unsigned int uu[4] = {uv.x, uv.y, uv.z, uv.w};
#pragma unroll
        for (int j2 = 0; j2 < 4; ++j2){
          a[8*i + 2*j2]     += bf2f((unsigned short)(uu[j2] & 0xffffu));
          a[8*i + 2*j2 + 1] += bf2f((unsigned short)(uu[j2] >> 16));
        }
      }
    }
    char* ar = aB + l*256;
    int asw = (l & 7) << 4;
#pragma unroll
    for (int i = 0; i < 8; ++i){
      int cb = q8*32 + 4*i;
      *(unsigned int*)(ar + (cb ^ asw)) = pk2(a[2*i]*inv, a[2*i+1]*inv);
    }
  }
  __syncthreads();

  // out = x + wo*attn + bo : wave w does 32 o-channels x 32 l
  int w = t >> 6, lane = t & 63, hi = lane >> 5, l31 = lane & 31;
  f32x16 acc;
#pragma unroll
  for (int i = 0; i < 16; ++i) acc[i] = 0.f;

#pragma unroll
  for (int kst = 0; kst < 8; ++kst){
    bf16x8 bfg = *(const bf16x8*)(aB + l31*256 + ((32*kst + 16*hi) ^ ((l31 & 7) << 4)));
    bf16x8 af = *(const bf16x8*)(wo_bf + (size_t)(32*w + l31)*C_D + 16*kst + 8*hi);
    acc = __builtin_amdgcn_mfma_f32_32x32x16_bf16(af, bfg, acc, 0, 0, 0);
  }
#pragma unroll
  for (int r = 0; r < 16; ++r){
    int o = 32*w + (r & 3) + 8*(r >> 2) + 4*hi;
    size_t idx = (size_t)(n*C_D + o)*L_D + l0 + l31;
    out[idx] = x[idx] + bo[o] + acc[r];
  }
}

extern "C" void kernel_launch(void* const* d_in, const int* in_sizes, int n_in,
                              void* d_out, int out_size, void* d_ws, size_t ws_size,
                              hipStream_t stream) {
  const float* x     = (const float*)d_in[0];
  const float* gamma = (const float*)d_in[1];
  const float* beta  = (const float*)d_in[2];
  const float* wq    = (const float*)d_in[3];
  const float* bq    = (const float*)d_in[4];
  const float* wk    = (const float*)d_in[5];
  const float* bk    = (const float*)d_in[6];
  const float* wv    = (const float*)d_in[7];
  const float* bv    = (const float*)d_in[8];
  const float* wo    = (const float*)d_in[9];
  const float* bo    = (const float*)d_in[10];
  float* out = (float*)d_out;

  char* ws = (char*)d_ws;
  unsigned short* q_ws  = (unsigned short*)(ws + 4096);
  unsigned short* k_ws  = q_ws + (size_t)N_B * L_D * C_D;
  unsigned short* v_ws  = k_ws + (size_t)N_B * L_D * C_D;
  unsigned short* po_ws = v_ws + (size_t)N_B * L_D * C_D;
  float* md_ws          = (float*)(po_ws + (size_t)N_B * 32 * SPLIT * 128 * 128);
  unsigned short* wbf   = (unsigned short*)(md_ws + (size_t)N_B * 32 * SPLIT * 128);
  unsigned short* xn_ws = wbf + 4*16384;     // [N][C][L] bf16, 4.2 MB

  gnw_k<<<192, 256, 0, stream>>>(x, gamma, beta, wq, wk, wv, wo, wbf, xn_ws);
  qkv_k<<<256, 256, 0, stream>>>(xn_ws, wbf, bq, bk, bv, q_ws, k_ws, v_ws);
  flash_split_k<<<256, 512, 0, stream>>>(q_ws, k_ws, v_ws, po_ws, md_ws);
  combine_k<<<512, 256, 0, stream>>>(po_ws, md_ws, x, wbf + 3*16384, bo, out);
}